// Round 6
// baseline (483.758 us; speedup 1.0000x reference)
//
#include <hip/hip_runtime.h>

// SelfAttentionLayer: B=8, N=2048, D=1024, fp32 in/out.
// R6: XCD-aware 1-D grid swizzles (xcd = L%8 heuristic) for all big GEMMs:
// S/PV pin batch->XCD (Q,K,vT become L2-resident); QKV pins 3 weight
// n-tiles/XCD. Plus R5's XOR-swizzled LDS (conflict-free) and depth-2
// global_load_lds pipeline (3 stages, manual vmcnt(4) barrier).

typedef _Float16 f16;
typedef _Float16 f16x4 __attribute__((ext_vector_type(4)));
typedef _Float16 f16x8 __attribute__((ext_vector_type(8)));
typedef float f32x4 __attribute__((ext_vector_type(4)));

#define Nn_ 2048
#define Dd 1024

typedef const __attribute__((address_space(1))) void gvoid;
typedef __attribute__((address_space(3))) void lvoid;

__device__ __forceinline__ void glds16(const void* g, void* l) {
    __builtin_amdgcn_global_load_lds((gvoid*)g, (lvoid*)l, 16, 0, 0);
}
__device__ __forceinline__ void bar_vm4() {
    asm volatile("s_waitcnt vmcnt(4)\n\ts_barrier" ::: "memory");
}
__device__ __forceinline__ void bar_vm0() {
    asm volatile("s_waitcnt vmcnt(0)\n\ts_barrier" ::: "memory");
}

// ---------------- fp32 -> fp16 convert ----------------
__global__ void cvt_kernel(const float4* __restrict__ in, f16x4* __restrict__ out, int n4) {
    int i = blockIdx.x * 256 + threadIdx.x;
    if (i >= n4) return;
    float4 f = in[i];
    f16x4 h;
    h.x = (_Float16)f.x; h.y = (_Float16)f.y; h.z = (_Float16)f.z; h.w = (_Float16)f.w;
    out[i] = h;
}

// ---------------- bias concat: bqkv[3072] = [bq|bk|bv] ----------------
__global__ void concat_bias(const float* __restrict__ bq, const float* __restrict__ bk,
                            const float* __restrict__ bv, float* __restrict__ o) {
    int i = blockIdx.x * 256 + threadIdx.x;
    if (i >= 3072) return;
    o[i] = (i < 1024) ? bq[i] : (i < 2048 ? bk[i - 1024] : bv[i - 2048]);
}

// ---------------- generic BT GEMM, 128x128 tile -----------------------------
// LDS layout: row r stored as 4 chunks of 8 f16; chunk q at physical q^((r>>1)&3).
// gpat: 0 = plain 3-D grid; 1 = S swizzle (bz=L&7, m-fast 16, n 16);
//       2 = PV swizzle (bz=L&7, n-fast 8, m 16); 3 = QKV (3 n-tiles/XCD, m-fast).
// mode 2: fp32 out row-major, no bias       (S-GEMM, PV->d_out)
// mode 3: merged QKV: by<8 -> qh, by<16 -> kh, else vT via LDS transpose.
__global__ __launch_bounds__(256) void gemm_bt(
    const f16* __restrict__ A, const f16* __restrict__ Bm,
    const float* __restrict__ bias, void* __restrict__ Cout,
    f16* __restrict__ qh, f16* __restrict__ kh, f16* __restrict__ vT,
    int K, int lda, int ldb, int ldc, int mode, int gpat,
    long aStride, long bStride, long cStride)
{
    __shared__ f16 sm[24576];   // 48KB: three 16KB stages (A 8KB + B 8KB)
    const int tid = threadIdx.x;
    const int lane = tid & 63, wid = tid >> 6;
    const int quad = lane >> 4, l16 = lane & 15;
    const int wm = (wid >> 1) * 64, wn = (wid & 1) * 64;

    int bx, by, bz;
    if (gpat == 0) { bx = blockIdx.x; by = blockIdx.y; bz = blockIdx.z; }
    else if (gpat == 1) {          // S: 2048 blocks; batch->XCD, m-fast
        int L = blockIdx.x; bz = L & 7; int r = L >> 3; bx = r & 15; by = r >> 4;
    } else if (gpat == 2) {        // PV: 1024 blocks; batch->XCD, n-fast
        int L = blockIdx.x; bz = L & 7; int r = L >> 3; by = r & 7; bx = r >> 3;
    } else {                       // QKV: 3072 blocks; 3 n-tiles/XCD, m-fast
        int L = blockIdx.x; int xc = L & 7; int r = L >> 3;
        int n3 = r % 3; bx = r / 3; by = xc * 3 + n3; bz = 0;
    }
    const long m0 = (long)bx * 128, n0 = (long)by * 128;
    A += (long)bz * aStride;
    Bm += (long)bz * bStride;

    const int ca = tid, cb = tid + 256;
    const long ar0 = m0 + (ca >> 2), ar1 = m0 + (cb >> 2);
    const long br0 = n0 + (ca >> 2), br1 = n0 + (cb >> 2);
    const int col0 = ((ca & 3) ^ ((ca >> 3) & 3)) * 8;
    const int col1 = ((cb & 3) ^ ((cb >> 3) & 3)) * 8;

    const f16* pa0 = A + ar0 * lda + col0;
    const f16* pa1 = A + ar1 * lda + col1;
    const f16* pb0 = Bm + br0 * ldb + col0;
    const f16* pb1 = Bm + br1 * ldb + col1;

    const int fo = (quad ^ ((l16 >> 1) & 3)) * 8;

    f32x4 acc[4][4];
#pragma unroll
    for (int i = 0; i < 4; i++)
#pragma unroll
        for (int j = 0; j < 4; j++) acc[i][j] = 0.0f;

    const int nk = K >> 5;
    glds16(pa0, sm + ca * 8);
    glds16(pa1, sm + cb * 8);
    glds16(pb0, sm + 4096 + ca * 8);
    glds16(pb1, sm + 4096 + cb * 8);
    if (nk > 1) {
        glds16(pa0 + 32, sm + 8192 + ca * 8);
        glds16(pa1 + 32, sm + 8192 + cb * 8);
        glds16(pb0 + 32, sm + 12288 + ca * 8);
        glds16(pb1 + 32, sm + 12288 + cb * 8);
    }

    int cur = 0;
    for (int it = 0; it < nk; ++it) {
        if (it + 1 < nk) bar_vm4(); else bar_vm0();
        if (it + 2 < nk) {
            f16* dst = sm + ((cur >= 1) ? (cur - 1) : (cur + 2)) * 8192;  // (cur+2)%3
            const int ko = (it + 2) * 32;
            glds16(pa0 + ko, dst + ca * 8);
            glds16(pa1 + ko, dst + cb * 8);
            glds16(pb0 + ko, dst + 4096 + ca * 8);
            glds16(pb1 + ko, dst + 4096 + cb * 8);
        }
        const f16* As = sm + cur * 8192;
        const f16* Bs = As + 4096;
        f16x8 af[4], bf[4];
#pragma unroll
        for (int rt = 0; rt < 4; rt++)
            af[rt] = *(const f16x8*)(As + (wm + rt * 16 + l16) * 32 + fo);
#pragma unroll
        for (int ct = 0; ct < 4; ct++)
            bf[ct] = *(const f16x8*)(Bs + (wn + ct * 16 + l16) * 32 + fo);
#pragma unroll
        for (int rt = 0; rt < 4; rt++)
#pragma unroll
            for (int ct = 0; ct < 4; ct++)
                acc[rt][ct] = __builtin_amdgcn_mfma_f32_16x16x32_f16(af[rt], bf[ct], acc[rt][ct], 0, 0, 0);
        cur = (cur == 2) ? 0 : cur + 1;
    }

    if (mode == 2) {
        float* O = (float*)Cout + (long)bz * cStride;
#pragma unroll
        for (int ct = 0; ct < 4; ct++) {
            long n = n0 + wn + ct * 16 + l16;
#pragma unroll
            for (int rt = 0; rt < 4; rt++) {
                long mb = m0 + wm + rt * 16 + quad * 4;
#pragma unroll
                for (int r = 0; r < 4; r++)
                    O[(mb + r) * ldc + n] = acc[rt][ct][r];
            }
        }
    } else {  // mode 3: merged QKV routing
        if (by < 16) {
            f16* O = (by < 8) ? qh : kh;
#pragma unroll
            for (int ct = 0; ct < 4; ct++) {
                long n = n0 + wn + ct * 16 + l16;
                float bs = bias[n];
                long n1 = n & 1023;
#pragma unroll
                for (int rt = 0; rt < 4; rt++) {
                    long mb = m0 + wm + rt * 16 + quad * 4;
#pragma unroll
                    for (int r = 0; r < 4; r++)
                        O[(mb + r) * 1024 + n1] = (f16)(acc[rt][ct][r] + bs);
                }
            }
        } else {
            // V: transpose 128m x 128n tile through LDS in two 64-col halves;
            // write vT[b][e][tok] with contiguous 256B rows.
            const long nb = n0 - 2048;
            const long vbase = (m0 >> 11) * (long)(Dd * Nn_) + (m0 & 2047);
#pragma unroll
            for (int h = 0; h < 2; ++h) {
                __syncthreads();
                if ((wid & 1) == h) {
#pragma unroll
                    for (int ct = 0; ct < 4; ++ct) {
                        int cl = ct * 16 + l16;                 // 0..63
                        float bs = bias[n0 + h * 64 + cl];
#pragma unroll
                        for (int rt = 0; rt < 4; rt++) {
                            int row = wm + rt * 16 + quad * 4;  // + r
#pragma unroll
                            for (int r = 0; r < 4; r++)
                                sm[cl * 136 + row + r] = (f16)(acc[rt][ct][r] + bs);
                        }
                    }
                }
                __syncthreads();
                const int rowi = tid >> 2, c4 = (tid & 3) * 32;
                f16* dst = vT + vbase + (nb + h * 64 + rowi) * (long)Nn_ + c4;
                const f16* src = sm + rowi * 136 + c4;
#pragma unroll
                for (int j = 0; j < 4; ++j)
                    *(f16x8*)(dst + j * 8) = *(const f16x8*)(src + j * 8);
            }
        }
    }
}

// ---------------- row softmax, P fp16 written in-place over S fp32 --------
__global__ __launch_bounds__(256) void softmax_rows(float* __restrict__ S) {
    const int row = blockIdx.x * 4 + (threadIdx.x >> 6);
    const int lane = threadIdx.x & 63;
    float* Sr = S + (long)row * 2048;
    const float4* R4 = (const float4*)Sr;
    float4 t[8];
#pragma unroll
    for (int i = 0; i < 8; i++) t[i] = R4[lane + 64 * i];
    float mx = -1e30f;
#pragma unroll
    for (int i = 0; i < 8; i++)
        mx = fmaxf(mx, fmaxf(fmaxf(t[i].x, t[i].y), fmaxf(t[i].z, t[i].w)));
#pragma unroll
    for (int off = 1; off < 64; off <<= 1) mx = fmaxf(mx, __shfl_xor(mx, off, 64));
    float se = 0.0f;
#pragma unroll
    for (int i = 0; i < 8; i++) {
        t[i].x = __expf(t[i].x - mx); t[i].y = __expf(t[i].y - mx);
        t[i].z = __expf(t[i].z - mx); t[i].w = __expf(t[i].w - mx);
        se += t[i].x + t[i].y + t[i].z + t[i].w;
    }
#pragma unroll
    for (int off = 1; off < 64; off <<= 1) se += __shfl_xor(se, off, 64);
    const float li = 1.0f / se;
    f16x4* P4 = (f16x4*)Sr;
#pragma unroll
    for (int i = 0; i < 8; i++) {
        f16x4 h;
        h.x = (_Float16)(t[i].x * li); h.y = (_Float16)(t[i].y * li);
        h.z = (_Float16)(t[i].z * li); h.w = (_Float16)(t[i].w * li);
        P4[lane + 64 * i] = h;
    }
}

extern "C" void kernel_launch(void* const* d_in, const int* in_sizes, int n_in,
                              void* d_out, int out_size, void* d_ws, size_t ws_size,
                              hipStream_t stream) {
    const float* x  = (const float*)d_in[0];
    const float* Wq = (const float*)d_in[1];
    const float* bq = (const float*)d_in[2];
    const float* Wk = (const float*)d_in[3];
    const float* bk = (const float*)d_in[4];
    const float* Wv = (const float*)d_in[5];
    const float* bv = (const float*)d_in[6];

    f16* wsh = (f16*)d_ws;
    dim3 blk(256);
    const bool full = ws_size >= 234881024ULL;  // 224 MiB full-batch path

    if (full) {
        f16* qh  = wsh;
        f16* kh  = wsh + 16777216;
        f16* vT  = wsh + 33554432;
        float* S = (float*)(wsh + 50331648);        // 33554432 floats
        f16* xh  = wsh + 50331648;                  // overlaid in S (dead later)
        f16* Wh  = wsh + 67108864;
        float* bqkv = (float*)(wsh + 70254592);

        cvt_kernel<<<16384, 256, 0, stream>>>((const float4*)x, (f16x4*)xh, 4194304);
        cvt_kernel<<<1024, 256, 0, stream>>>((const float4*)Wq, (f16x4*)Wh, 262144);
        cvt_kernel<<<1024, 256, 0, stream>>>((const float4*)Wk, (f16x4*)(Wh + 1048576), 262144);
        cvt_kernel<<<1024, 256, 0, stream>>>((const float4*)Wv, (f16x4*)(Wh + 2097152), 262144);
        concat_bias<<<12, 256, 0, stream>>>(bq, bk, bv, bqkv);

        gemm_bt<<<3072, blk, 0, stream>>>(
            xh, Wh, bqkv, nullptr, qh, kh, vT,
            1024, 1024, 1024, 0, 3, 3, 0, 0, 0);
        gemm_bt<<<2048, blk, 0, stream>>>(
            qh, kh, nullptr, S, nullptr, nullptr, nullptr,
            1024, 1024, 1024, 2048, 2, 1,
            (long)Nn_ * Dd, (long)Nn_ * Dd, (long)Nn_ * Nn_);
        softmax_rows<<<4096, 256, 0, stream>>>(S);
        gemm_bt<<<1024, blk, 0, stream>>>(
            (const f16*)S, vT, nullptr, d_out, nullptr, nullptr, nullptr,
            2048, 4096, 2048, 1024, 2, 2,
            (long)Nn_ * 4096, (long)Dd * Nn_, (long)Nn_ * Dd);
    } else {
        f16* xh  = wsh;
        f16* Wh  = wsh + 16777216;
        float* bqkv = (float*)(wsh + 19922944);
        f16* qh  = wsh + 19929088;
        f16* kh  = qh + 16777216;
        f16* vT  = kh + 16777216;
        float* S = (float*)(vT + 16777216);

        cvt_kernel<<<16384, 256, 0, stream>>>((const float4*)x, (f16x4*)xh, 4194304);
        cvt_kernel<<<1024, 256, 0, stream>>>((const float4*)Wq, (f16x4*)Wh, 262144);
        cvt_kernel<<<1024, 256, 0, stream>>>((const float4*)Wk, (f16x4*)(Wh + 1048576), 262144);
        cvt_kernel<<<1024, 256, 0, stream>>>((const float4*)Wv, (f16x4*)(Wh + 2097152), 262144);
        concat_bias<<<12, 256, 0, stream>>>(bq, bk, bv, bqkv);

        gemm_bt<<<dim3(128, 24, 1), blk, 0, stream>>>(
            xh, Wh, bqkv, nullptr, qh, kh, vT,
            1024, 1024, 1024, 0, 3, 0, 0, 0, 0);

        for (int h = 0; h < 2; ++h) {
            const long b0 = 4L * h;
            gemm_bt<<<dim3(16, 16, 4), blk, 0, stream>>>(
                qh + b0 * Nn_ * Dd, kh + b0 * Nn_ * Dd, nullptr, S,
                nullptr, nullptr, nullptr,
                1024, 1024, 1024, 2048, 2, 0,
                (long)Nn_ * Dd, (long)Nn_ * Dd, (long)Nn_ * Nn_);
            softmax_rows<<<2048, 256, 0, stream>>>(S);
            gemm_bt<<<dim3(16, 8, 4), blk, 0, stream>>>(
                (const f16*)S, vT + b0 * Dd * Nn_, nullptr,
                (float*)d_out + b0 * Nn_ * Dd, nullptr, nullptr, nullptr,
                2048, 4096, 2048, 1024, 2, 0,
                (long)Nn_ * 4096, (long)Dd * Nn_, (long)Nn_ * Dd);
        }
    }
}

// Round 7
// 439.345 us; speedup vs baseline: 1.1011x; 1.1011x over previous
//
#include <hip/hip_runtime.h>

// SelfAttentionLayer: B=8, N=2048, D=1024, fp32 in/out.
// R7: 128m x 256n tiles, 512 threads (8 waves, 2m x 4n), 3-stage depth-2
// global_load_lds pipeline (vmcnt(3) barrier), XOR-swizzled LDS. Plain 3-D
// grids (R6 XCD swizzle reverted — it regressed). Rationale: streamed-A
// traffic halves (B-tiles stay L2-hot across consecutive x-blocks).

typedef _Float16 f16;
typedef _Float16 f16x4 __attribute__((ext_vector_type(4)));
typedef _Float16 f16x8 __attribute__((ext_vector_type(8)));
typedef float f32x4 __attribute__((ext_vector_type(4)));

#define Nn_ 2048
#define Dd 1024

typedef const __attribute__((address_space(1))) void gvoid;
typedef __attribute__((address_space(3))) void lvoid;

__device__ __forceinline__ void glds16(const void* g, void* l) {
    __builtin_amdgcn_global_load_lds((gvoid*)g, (lvoid*)l, 16, 0, 0);
}
__device__ __forceinline__ void bar_vm3() {
    asm volatile("s_waitcnt vmcnt(3)\n\ts_barrier" ::: "memory");
}
__device__ __forceinline__ void bar_vm0() {
    asm volatile("s_waitcnt vmcnt(0)\n\ts_barrier" ::: "memory");
}

// ---------------- fp32 -> fp16 convert ----------------
__global__ void cvt_kernel(const float4* __restrict__ in, f16x4* __restrict__ out, int n4) {
    int i = blockIdx.x * 256 + threadIdx.x;
    if (i >= n4) return;
    float4 f = in[i];
    f16x4 h;
    h.x = (_Float16)f.x; h.y = (_Float16)f.y; h.z = (_Float16)f.z; h.w = (_Float16)f.w;
    out[i] = h;
}

// ---------------- bias concat: bqkv[3072] = [bq|bk|bv] ----------------
__global__ void concat_bias(const float* __restrict__ bq, const float* __restrict__ bk,
                            const float* __restrict__ bv, float* __restrict__ o) {
    int i = blockIdx.x * 256 + threadIdx.x;
    if (i >= 3072) return;
    o[i] = (i < 1024) ? bq[i] : (i < 2048 ? bk[i - 1024] : bv[i - 2048]);
}

// ---------------- BT GEMM, 128m x 256n tile, 512 threads --------------------
// LDS stage: A 128x32 f16 (8KB) + B 256x32 f16 (16KB) = 24KB; 3 stages = 72KB.
// Row r stored as 4 chunks of 8 f16; chunk q at physical q^((r>>1)&3).
// mode 2: fp32 out row-major, no bias       (S-GEMM, PV->d_out)
// mode 3: merged QKV (N=3072, 12 n-tiles): by<4 -> qh, by<8 -> kh,
//         else vT[b][e][tok] via LDS transpose (coalesced stores).
__global__ __launch_bounds__(512) void gemm_bt(
    const f16* __restrict__ A, const f16* __restrict__ Bm,
    const float* __restrict__ bias, void* __restrict__ Cout,
    f16* __restrict__ qh, f16* __restrict__ kh, f16* __restrict__ vT,
    int K, int lda, int ldb, int ldc, int mode,
    long aStride, long bStride, long cStride)
{
    __shared__ f16 sm[36864];   // 72KB: three 24KB stages
    const int tid = threadIdx.x;
    const int lane = tid & 63, wid = tid >> 6;
    const int quad = lane >> 4, l16 = lane & 15;
    const int wm = (wid & 1) * 64;        // 2 m-positions
    const int wn = (wid >> 1) * 64;       // 4 n-positions
    const long m0 = (long)blockIdx.x * 128, n0 = (long)blockIdx.y * 256;
    const int bz = blockIdx.z;
    A += (long)bz * aStride;
    Bm += (long)bz * bStride;

    // loaders: A la=tid (512 loads), B lb=tid and tid+512 (1024 loads)
    const int la = tid, lb0 = tid, lb1 = tid + 512;
    const long arow = m0 + (la >> 2);
    const long brow0 = n0 + (lb0 >> 2), brow1 = n0 + (lb1 >> 2);
    const int colA  = ((la & 3) ^ ((la >> 3) & 3)) * 8;
    const int colB0 = ((lb0 & 3) ^ ((lb0 >> 3) & 3)) * 8;
    const int colB1 = ((lb1 & 3) ^ ((lb1 >> 3) & 3)) * 8;

    const f16* pa  = A + arow * lda + colA;
    const f16* pb0 = Bm + brow0 * ldb + colB0;
    const f16* pb1 = Bm + brow1 * ldb + colB1;

    const int fo = (quad ^ ((l16 >> 1) & 3)) * 8;   // fragment chunk offset

    f32x4 acc[4][4];
#pragma unroll
    for (int i = 0; i < 4; i++)
#pragma unroll
        for (int j = 0; j < 4; j++) acc[i][j] = 0.0f;

    const int nk = K >> 5;
    // prologue: tiles 0,1 -> stages 0,1  (stage stride 12288 f16; Bs at +4096)
    glds16(pa, sm + la * 8);
    glds16(pb0, sm + 4096 + lb0 * 8);
    glds16(pb1, sm + 4096 + lb1 * 8);
    if (nk > 1) {
        glds16(pa + 32, sm + 12288 + la * 8);
        glds16(pb0 + 32, sm + 16384 + lb0 * 8);
        glds16(pb1 + 32, sm + 16384 + lb1 * 8);
    }

    int cur = 0;
    for (int it = 0; it < nk; ++it) {
        if (it + 1 < nk) bar_vm3(); else bar_vm0();
        if (it + 2 < nk) {
            f16* dst = sm + ((cur >= 1) ? (cur - 1) : 2) * 12288;  // (cur+2)%3
            const int ko = (it + 2) * 32;
            glds16(pa + ko, dst + la * 8);
            glds16(pb0 + ko, dst + 4096 + lb0 * 8);
            glds16(pb1 + ko, dst + 4096 + lb1 * 8);
        }
        const f16* As = sm + cur * 12288;
        const f16* Bs = As + 4096;
        f16x8 af[4], bf[4];
#pragma unroll
        for (int rt = 0; rt < 4; rt++)
            af[rt] = *(const f16x8*)(As + (wm + rt * 16 + l16) * 32 + fo);
#pragma unroll
        for (int ct = 0; ct < 4; ct++)
            bf[ct] = *(const f16x8*)(Bs + (wn + ct * 16 + l16) * 32 + fo);
#pragma unroll
        for (int rt = 0; rt < 4; rt++)
#pragma unroll
            for (int ct = 0; ct < 4; ct++)
                acc[rt][ct] = __builtin_amdgcn_mfma_f32_16x16x32_f16(af[rt], bf[ct], acc[rt][ct], 0, 0, 0);
        cur = (cur == 2) ? 0 : cur + 1;
    }

    if (mode == 2) {
        float* O = (float*)Cout + (long)bz * cStride;
#pragma unroll
        for (int ct = 0; ct < 4; ct++) {
            long n = n0 + wn + ct * 16 + l16;
#pragma unroll
            for (int rt = 0; rt < 4; rt++) {
                long mb = m0 + wm + rt * 16 + quad * 4;
#pragma unroll
                for (int r = 0; r < 4; r++)
                    O[(mb + r) * ldc + n] = acc[rt][ct][r];
            }
        }
    } else {  // mode 3: merged QKV routing (n-tile = 256 wide)
        if (blockIdx.y < 8) {
            f16* O = (blockIdx.y < 4) ? qh : kh;
#pragma unroll
            for (int ct = 0; ct < 4; ct++) {
                long n = n0 + wn + ct * 16 + l16;
                float bs = bias[n];
                long n1 = n & 1023;
#pragma unroll
                for (int rt = 0; rt < 4; rt++) {
                    long mb = m0 + wm + rt * 16 + quad * 4;
#pragma unroll
                    for (int r = 0; r < 4; r++)
                        O[(mb + r) * 1024 + n1] = (f16)(acc[rt][ct][r] + bs);
                }
            }
        } else {
            // V: transpose 128m x 256n tile through LDS in four 64-col groups;
            // write vT[b][e][tok] with contiguous rows.
            const long nb = n0 - 2048;
            const long vbase = (m0 >> 11) * (long)(Dd * Nn_) + (m0 & 2047);
#pragma unroll
            for (int g = 0; g < 4; ++g) {
                __syncthreads();
                if ((wid >> 1) == g) {   // 2 waves own this 64-col group
#pragma unroll
                    for (int ct = 0; ct < 4; ++ct) {
                        int cl = ct * 16 + l16;                 // 0..63
                        float bs = bias[n0 + g * 64 + cl];
#pragma unroll
                        for (int rt = 0; rt < 4; rt++) {
                            int row = wm + rt * 16 + quad * 4;  // + r, 0..127
#pragma unroll
                            for (int r = 0; r < 4; r++)
                                sm[cl * 136 + row + r] = (f16)(acc[rt][ct][r] + bs);
                        }
                    }
                }
                __syncthreads();
                const int rowi = tid >> 3, c = (tid & 7) * 16;
                f16* dst = vT + vbase + (nb + g * 64 + rowi) * (long)Nn_ + c;
                const f16* src = sm + rowi * 136 + c;
                *(f16x8*)(dst) = *(const f16x8*)(src);
                *(f16x8*)(dst + 8) = *(const f16x8*)(src + 8);
            }
        }
    }
}

// ---------------- row softmax, P fp16 written in-place over S fp32 --------
__global__ __launch_bounds__(256) void softmax_rows(float* __restrict__ S) {
    const int row = blockIdx.x * 4 + (threadIdx.x >> 6);
    const int lane = threadIdx.x & 63;
    float* Sr = S + (long)row * 2048;
    const float4* R4 = (const float4*)Sr;
    float4 t[8];
#pragma unroll
    for (int i = 0; i < 8; i++) t[i] = R4[lane + 64 * i];
    float mx = -1e30f;
#pragma unroll
    for (int i = 0; i < 8; i++)
        mx = fmaxf(mx, fmaxf(fmaxf(t[i].x, t[i].y), fmaxf(t[i].z, t[i].w)));
#pragma unroll
    for (int off = 1; off < 64; off <<= 1) mx = fmaxf(mx, __shfl_xor(mx, off, 64));
    float se = 0.0f;
#pragma unroll
    for (int i = 0; i < 8; i++) {
        t[i].x = __expf(t[i].x - mx); t[i].y = __expf(t[i].y - mx);
        t[i].z = __expf(t[i].z - mx); t[i].w = __expf(t[i].w - mx);
        se += t[i].x + t[i].y + t[i].z + t[i].w;
    }
#pragma unroll
    for (int off = 1; off < 64; off <<= 1) se += __shfl_xor(se, off, 64);
    const float li = 1.0f / se;
    f16x4* P4 = (f16x4*)Sr;
#pragma unroll
    for (int i = 0; i < 8; i++) {
        f16x4 h;
        h.x = (_Float16)(t[i].x * li); h.y = (_Float16)(t[i].y * li);
        h.z = (_Float16)(t[i].z * li); h.w = (_Float16)(t[i].w * li);
        P4[lane + 64 * i] = h;
    }
}

extern "C" void kernel_launch(void* const* d_in, const int* in_sizes, int n_in,
                              void* d_out, int out_size, void* d_ws, size_t ws_size,
                              hipStream_t stream) {
    const float* x  = (const float*)d_in[0];
    const float* Wq = (const float*)d_in[1];
    const float* bq = (const float*)d_in[2];
    const float* Wk = (const float*)d_in[3];
    const float* bk = (const float*)d_in[4];
    const float* Wv = (const float*)d_in[5];
    const float* bv = (const float*)d_in[6];

    f16* wsh = (f16*)d_ws;
    dim3 blk(512);
    const bool full = ws_size >= 234881024ULL;  // 224 MiB full-batch path

    if (full) {
        f16* qh  = wsh;
        f16* kh  = wsh + 16777216;
        f16* vT  = wsh + 33554432;
        float* S = (float*)(wsh + 50331648);        // 33554432 floats
        f16* xh  = wsh + 50331648;                  // overlaid in S (dead later)
        f16* Wh  = wsh + 67108864;
        float* bqkv = (float*)(wsh + 70254592);

        cvt_kernel<<<16384, 256, 0, stream>>>((const float4*)x, (f16x4*)xh, 4194304);
        cvt_kernel<<<1024, 256, 0, stream>>>((const float4*)Wq, (f16x4*)Wh, 262144);
        cvt_kernel<<<1024, 256, 0, stream>>>((const float4*)Wk, (f16x4*)(Wh + 1048576), 262144);
        cvt_kernel<<<1024, 256, 0, stream>>>((const float4*)Wv, (f16x4*)(Wh + 2097152), 262144);
        concat_bias<<<12, 256, 0, stream>>>(bq, bk, bv, bqkv);

        // QKV: M=16384 (128 m-tiles), N=3072 (12 n-tiles)
        gemm_bt<<<dim3(128, 12, 1), blk, 0, stream>>>(
            xh, Wh, bqkv, nullptr, qh, kh, vT,
            1024, 1024, 1024, 0, 3, 0, 0, 0);
        // S = Q K^T : per batch 16 m-tiles x 8 n-tiles
        gemm_bt<<<dim3(16, 8, 8), blk, 0, stream>>>(
            qh, kh, nullptr, S, nullptr, nullptr, nullptr,
            1024, 1024, 1024, 2048, 2,
            (long)Nn_ * Dd, (long)Nn_ * Dd, (long)Nn_ * Nn_);
        softmax_rows<<<4096, 256, 0, stream>>>(S);
        // out = P V : per batch 16 m-tiles x 4 n-tiles
        gemm_bt<<<dim3(16, 4, 8), blk, 0, stream>>>(
            (const f16*)S, vT, nullptr, d_out, nullptr, nullptr, nullptr,
            2048, 4096, 2048, 1024, 2,
            (long)Nn_ * 4096, (long)Dd * Nn_, (long)Nn_ * Dd);
    } else {
        f16* xh  = wsh;
        f16* Wh  = wsh + 16777216;
        float* bqkv = (float*)(wsh + 19922944);
        f16* qh  = wsh + 19929088;
        f16* kh  = qh + 16777216;
        f16* vT  = kh + 16777216;
        float* S = (float*)(vT + 16777216);

        cvt_kernel<<<16384, 256, 0, stream>>>((const float4*)x, (f16x4*)xh, 4194304);
        cvt_kernel<<<1024, 256, 0, stream>>>((const float4*)Wq, (f16x4*)Wh, 262144);
        cvt_kernel<<<1024, 256, 0, stream>>>((const float4*)Wk, (f16x4*)(Wh + 1048576), 262144);
        cvt_kernel<<<1024, 256, 0, stream>>>((const float4*)Wv, (f16x4*)(Wh + 2097152), 262144);
        concat_bias<<<12, 256, 0, stream>>>(bq, bk, bv, bqkv);

        gemm_bt<<<dim3(128, 12, 1), blk, 0, stream>>>(
            xh, Wh, bqkv, nullptr, qh, kh, vT,
            1024, 1024, 1024, 0, 3, 0, 0, 0);

        for (int h = 0; h < 2; ++h) {
            const long b0 = 4L * h;
            gemm_bt<<<dim3(16, 8, 4), blk, 0, stream>>>(
                qh + b0 * Nn_ * Dd, kh + b0 * Nn_ * Dd, nullptr, S,
                nullptr, nullptr, nullptr,
                1024, 1024, 1024, 2048, 2,
                (long)Nn_ * Dd, (long)Nn_ * Dd, (long)Nn_ * Nn_);
            softmax_rows<<<2048, 256, 0, stream>>>(S);
            gemm_bt<<<dim3(16, 4, 4), blk, 0, stream>>>(
                (const f16*)S, vT + b0 * Dd * Nn_, nullptr,
                (float*)d_out + b0 * Nn_ * Dd, nullptr, nullptr, nullptr,
                2048, 4096, 2048, 1024, 2,
                (long)Nn_ * 4096, (long)Dd * Nn_, (long)Nn_ * Dd);
        }
    }
}